// Round 6
// baseline (533.565 us; speedup 1.0000x reference)
//
#include <hip/hip_runtime.h>
#include <hip/hip_bf16.h>
#include <cstddef>
#include <cstdint>

#define B_ 2
#define D_ 12
#define H_ 200
#define W_ 200
#define HW_ (H_ * W_)
#define DHW_ (D_ * H_ * W_)
#define CELLS_ (B_ * D_ * H_ * W_)   // 960000
#define N_ 60000
#define CIN_ 2
#define COUT_ 64
#define K27 27
#define EPS_ 1e-5f
#define ZCHUNK 6                      // z-planes per workgroup (12 % 6 == 0)

typedef float f32x4 __attribute__((ext_vector_type(4)));

// ---------------------------------------------------------------------------
// Kernel A: dense cell -> point_id map. scatter[13][n] is the identity tap.
// ---------------------------------------------------------------------------
__global__ void fill_map_kernel(const int* __restrict__ scatter,
                                int* __restrict__ map) {
    int n = blockIdx.x * blockDim.x + threadIdx.x;
    if (n >= N_) return;
    map[scatter[13 * N_ + n]] = n;
}

// ---------------------------------------------------------------------------
// DPP 16-lane allreduce-add (VALU pipe, no LDS).
// ---------------------------------------------------------------------------
template <int CTRL>
__device__ __forceinline__ float dpp_add(float v) {
    int t = __builtin_amdgcn_update_dpp(
        0, __float_as_int(v), CTRL, 0xF, 0xF, true);
    return v + __int_as_float(t);
}
__device__ __forceinline__ float row16_allreduce_add(float v) {
    v = dpp_add<0x140>(v);  // row_mirror
    v = dpp_add<0x141>(v);  // row_half_mirror
    v = dpp_add<0x4E>(v);   // quad_perm i^2
    v = dpp_add<0xB1>(v);   // quad_perm i^1
    return v;
}

// ---------------------------------------------------------------------------
// Kernel B: round-4 structure (16 lanes/cell, ZCHUNK z-planes), wrapped in a
// runtime `reps` loop for this MEASUREMENT round. reps=4 makes this dispatch
// ~4x its real cost so it surfaces in the rocprof top-5 with full counters,
// and (dur - dur_round4)/3 gives its exact per-rep cost. Output writes are
// idempotent; the asm memory clobber prevents cross-rep CSE.
// ---------------------------------------------------------------------------
__global__ __launch_bounds__(256) void gather_cell16_kernel(
        const float* __restrict__ feat,
        const float* __restrict__ weight,
        const float* __restrict__ gamma,
        const float* __restrict__ beta,
        const int* __restrict__ map,
        float* __restrict__ out,
        int reps) {
    const int tid = threadIdx.x;
    const int slot = tid >> 4;              // cell slot within block, 0..15
    const int q    = tid & 15;              // lane within 16-lane group
    const int gw   = slot & 3;              // group within wave, 0..3

    const int x  = blockIdx.x * 16 + slot;  // cell x
    const int y  = blockIdx.y;              // cell y
    const int zi = blockIdx.z;              // z-chunk index, 0..3
    const int bz0 = zi * ZCHUNK;            // first bz of this chunk
    const int b  = bz0 >= D_ ? 1 : 0;       // chunk never straddles b
    const int z0 = bz0 - b * D_;

    const bool cell_ok = (x < W_);

    // tap decomposition for this lane's two probe taps (loop-invariant)
    const int fz1 = q / 9,  t1 = q - fz1 * 9;
    const int fy1 = t1 / 3, fx1 = t1 - fy1 * 3;
    const int tap2 = q + 16;
    const int fz2 = tap2 / 9,  t2 = tap2 - fz2 * 9;
    const int fy2 = t2 / 3,    fx2 = t2 - fy2 * 3;
    const bool has2 = (q < K27 - 16);

    // loop-invariant probe coords in x,y
    const int py1 = y + fy1 - 1, px1 = x + fx1 - 1;
    const int py2 = y + fy2 - 1, px2 = x + fx2 - 1;
    const bool xy1 = cell_ok && py1 >= 0 && py1 < H_ && px1 >= 0 && px1 < W_;
    const bool xy2 = has2 && cell_ok && py2 >= 0 && py2 < H_ &&
                     px2 >= 0 && px2 < W_;

    float4 gm = *reinterpret_cast<const float4*>(&gamma[q * 4]);
    float4 bt = *reinterpret_cast<const float4*>(&beta[q * 4]);

    for (int rep = 0; rep < reps; ++rep) {
        // prevent cross-rep CSE/hoisting: loads below must re-execute
        asm volatile("" ::: "memory");

        for (int j = 0; j < ZCHUNK; ++j) {
            const int z  = z0 + j;
            const int bz = bz0 + j;

            // ---- probe round 1: taps 0..15 ----
            int n1 = -1;
            {
                int pz = z + fz1 - 1;
                if (xy1 && pz >= 0 && pz < D_)
                    n1 = map[((b * D_ + pz) * H_ + py1) * W_ + px1];
            }
            // ---- probe round 2: taps 16..26 ----
            int n2 = -1;
            {
                int pz = z + fz2 - 1;
                if (xy2 && pz >= 0 && pz < D_)
                    n2 = map[((b * D_ + pz) * H_ + py2) * W_ + px2];
            }

            // ---- feature forwarding ----
            float2 f1 = {0.f, 0.f}, f2 = {0.f, 0.f};
            if (n1 >= 0)
                f1 = *reinterpret_cast<const float2*>(&feat[n1 * CIN_]);
            if (n2 >= 0)
                f2 = *reinterpret_cast<const float2*>(&feat[n2 * CIN_]);

            unsigned long long ball1 = __ballot(n1 >= 0);
            unsigned long long ball2 = __ballot(n2 >= 0);
            const int shift = gw * 16;
            unsigned int mask =
                  (unsigned int)((ball1 >> shift) & 0xFFFFull)
                | ((unsigned int)((ball2 >> shift) & 0x7FFull) << 16);
            const bool active = (mask != 0u);

            // ---- gather-conv over actual hits ----
            float4 acc = {0.f, 0.f, 0.f, 0.f};
            while (mask) {
                int l = __ffs(mask) - 1;    // tap index == weight k
                mask &= mask - 1;
                int src = (gw << 4) + (l & 15);
                float fx = __shfl((l < 16) ? f1.x : f2.x, src, 64);
                float fy = __shfl((l < 16) ? f1.y : f2.y, src, 64);
                const float* wk = &weight[l * (CIN_ * COUT_) + q * 4];
                float4 w0 = *reinterpret_cast<const float4*>(wk);
                float4 w1 = *reinterpret_cast<const float4*>(wk + COUT_);
                acc.x += fx * w0.x + fy * w1.x;
                acc.y += fx * w0.y + fy * w1.y;
                acc.z += fx * w0.z + fy * w1.z;
                acc.w += fx * w0.w + fy * w1.w;
            }

            // ---- LayerNorm via DPP allreduce ----
            float s  = acc.x + acc.y + acc.z + acc.w;
            float s2 = acc.x * acc.x + acc.y * acc.y + acc.z * acc.z
                     + acc.w * acc.w;
            s  = row16_allreduce_add(s);
            s2 = row16_allreduce_add(s2);
            float mu  = s * (1.0f / COUT_);
            float var = s2 * (1.0f / COUT_) - mu * mu;
            float inv = rsqrtf(var + EPS_);

            f32x4 r;
            if (active) {
                r.x = fmaxf((acc.x - mu) * inv * gm.x + bt.x, 0.0f);
                r.y = fmaxf((acc.y - mu) * inv * gm.y + bt.y, 0.0f);
                r.z = fmaxf((acc.z - mu) * inv * gm.z + bt.z, 0.0f);
                r.w = fmaxf((acc.w - mu) * inv * gm.w + bt.w, 0.0f);
            } else {
                r.x = r.y = r.z = r.w = 0.0f;
            }

            if (cell_ok) {
                size_t obase =
                    ((size_t)((bz * H_ + y) * W_ + x)) * COUT_ + q * 4;
                __builtin_nontemporal_store(
                    r, reinterpret_cast<f32x4*>(&out[obase]));
            }
        }
    }
}

extern "C" void kernel_launch(void* const* d_in, const int* in_sizes, int n_in,
                              void* d_out, int out_size, void* d_ws, size_t ws_size,
                              hipStream_t stream) {
    const float* feat    = (const float*)d_in[0];   // (N, 2)
    const float* weight  = (const float*)d_in[1];   // (27, 2, 64)
    const float* gamma   = (const float*)d_in[2];   // (64,)
    const float* beta    = (const float*)d_in[3];   // (64,)
    const int*   scatter = (const int*)d_in[4];     // (27, N)
    float* out = (float*)d_out;                     // (CELLS, 64)

    int* map = (int*)d_ws;                          // CELLS * 4 B = 3.84 MB

    (void)hipMemsetAsync(map, 0xFF, (size_t)CELLS_ * sizeof(int), stream);
    {
        int block = 256;
        int grid = (N_ + block - 1) / block;
        fill_map_kernel<<<grid, block, 0, stream>>>(scatter, map);
    }

    // MEASUREMENT: reps=4 so the gather dispatch dominates rocprof top-5 and
    // the dur_us slope isolates its true per-rep cost.
    {
        dim3 block(256, 1, 1);
        dim3 grid((W_ + 15) / 16, H_, (B_ * D_) / ZCHUNK);  // 13 x 200 x 4
        gather_cell16_kernel<<<grid, block, 0, stream>>>(feat, weight, gamma,
                                                         beta, map, out, 4);
    }
}

// Round 8
// 279.210 us; speedup vs baseline: 1.9110x; 1.9110x over previous
//
#include <hip/hip_runtime.h>
#include <hip/hip_bf16.h>
#include <cstddef>
#include <cstdint>

#define B_ 2
#define D_ 12
#define H_ 200
#define W_ 200
#define HW_ (H_ * W_)
#define DHW_ (D_ * H_ * W_)
#define CELLS_ (B_ * D_ * H_ * W_)   // 960000
#define N_ 60000
#define CIN_ 2
#define COUT_ 64
#define K27 27
#define EPS_ 1e-5f
#define ZCHUNK 6                      // z-planes per workgroup (12 % 6 == 0)

typedef float f32x4 __attribute__((ext_vector_type(4)));
typedef __fp16 h16x2 __attribute__((ext_vector_type(2)));   // matches builtins

union h2u { h16x2 h; int u; };
__device__ __forceinline__ int pack_h2(float a, float b) {
    h2u t; t.h = __builtin_amdgcn_cvt_pkrtz(a, b); return t.u;
}
__device__ __forceinline__ h16x2 as_h2(int v) { h2u t; t.u = v; return t.h; }

// ---------------------------------------------------------------------------
// Kernel A: dense cell -> point_id map. scatter[13][n] is the identity tap.
// ---------------------------------------------------------------------------
__global__ void fill_map_kernel(const int* __restrict__ scatter,
                                int* __restrict__ map) {
    int n = blockIdx.x * blockDim.x + threadIdx.x;
    if (n >= N_) return;
    map[scatter[13 * N_ + n]] = n;
}

// ---------------------------------------------------------------------------
// DPP 16-lane allreduce-add (VALU pipe, no LDS).
// ---------------------------------------------------------------------------
template <int CTRL>
__device__ __forceinline__ float dpp_add(float v) {
    int t = __builtin_amdgcn_update_dpp(
        0, __float_as_int(v), CTRL, 0xF, 0xF, true);
    return v + __int_as_float(t);
}
__device__ __forceinline__ float row16_allreduce_add(float v) {
    v = dpp_add<0x140>(v);  // row_mirror
    v = dpp_add<0x141>(v);  // row_half_mirror
    v = dpp_add<0x4E>(v);   // quad_perm i^2
    v = dpp_add<0xB1>(v);   // quad_perm i^1
    return v;
}

// ---------------------------------------------------------------------------
// Kernel B, round-8 (= round-7 intent, type-fixed): VALU-cut version.
//  - ROLLING-Z PROBES: per z-iter probe only the NEW plane (9 taps, lanes
//    q<9, wave-uniform plane index -> scalar z-bounds, 1 probe load + 1
//    ballot instead of 2+2). 3 plane states rotate in registers.
//  - FP16 DOT2 INNER LOOP: feature packed to half2 at probe time; weights
//    packed (w0[c],w1[c]) -> half2 in LDS (6.9 KB). Per hit: 1 shuffled
//    half2 + 1 ds_read_b128 + 4 v_dot2_f32_f16 (fp32 accumulate) replacing
//    2 global loads + 8 scalar FMAs.
// ---------------------------------------------------------------------------
__global__ __launch_bounds__(256) void gather_cell16_kernel(
        const float* __restrict__ feat,
        const float* __restrict__ weight,
        const float* __restrict__ gamma,
        const float* __restrict__ beta,
        const int* __restrict__ map,
        float* __restrict__ out) {
    __shared__ int wlds[K27 * COUT_];       // half2(w0[c], w1[c]) per (k,c)

    const int tid = threadIdx.x;

    // ---- stage packed fp16 weights in LDS (one-time, 27*64 entries) ----
    #pragma unroll
    for (int i = 0; i < 7; ++i) {
        int id = tid + i * 256;
        if (id < K27 * COUT_) {
            int k = id >> 6, c = id & 63;
            float w0 = weight[k * (CIN_ * COUT_) + c];
            float w1 = weight[k * (CIN_ * COUT_) + COUT_ + c];
            wlds[id] = pack_h2(w0, w1);
        }
    }
    __syncthreads();

    const int slot = tid >> 4;              // cell slot within block, 0..15
    const int q    = tid & 15;              // lane within 16-lane group
    const int gw   = slot & 3;              // group within wave, 0..3
    const int shift = gw * 16;

    const int x  = blockIdx.x * 16 + slot;  // cell x
    const int y  = blockIdx.y;              // cell y
    const int bz0 = blockIdx.z * ZCHUNK;    // first bz of this chunk
    const int b  = bz0 >= D_ ? 1 : 0;       // chunk never straddles b
    const int z0 = bz0 - b * D_;
    const bool cell_ok = (x < W_);

    // 9-tap (fy,fx) decomposition for probing lanes q<9 (loop-invariant)
    const int fy = q / 3, fx = q - fy * 3;  // junk for q>=9, masked below
    const int py = y + fy - 1, px = x + fx - 1;
    const bool xy9 = (q < 9) && cell_ok &&
                     py >= 0 && py < H_ && px >= 0 && px < W_;
    const int off_xy = py * W_ + px;
    const int bD = b * D_;

    f32x4 gm = *reinterpret_cast<const f32x4*>(&gamma[q * 4]);
    f32x4 bt = *reinterpret_cast<const f32x4*>(&beta[q * 4]);

    int m9s[3];     // per-group 9-bit hit masks for planes z-1, z, z+1
    int fhs[3];     // this lane's packed half2 feature for its plane tap

    // probe one z-plane: 9 taps on lanes q<9; plane index is wave-uniform
    auto probe = [&](int pz, int& m9, int& fh) {
        int n = -1;
        if ((unsigned)pz < (unsigned)D_ && xy9)
            n = map[(bD + pz) * HW_ + off_xy];
        unsigned long long ball = __ballot(n >= 0);
        m9 = (int)((ball >> shift) & 0x1FFull);
        fh = 0;
        if (n >= 0) {
            float2 fv = *reinterpret_cast<const float2*>(&feat[n * CIN_]);
            fh = pack_h2(fv.x, fv.y);
        }
    };

    probe(z0 - 1, m9s[0], fhs[0]);          // plane below first cell
    probe(z0,     m9s[1], fhs[1]);          // first cell's own plane

    #pragma unroll
    for (int j = 0; j < ZCHUNK; ++j) {
        const int sA = j % 3, sB = (j + 1) % 3, sC = (j + 2) % 3;
        probe(z0 + j + 1, m9s[sC], fhs[sC]);    // only the new plane

        // combined 27-bit mask; bit l = fz*9 + (fy*3+fx) == weight index
        unsigned int mask = (unsigned)m9s[sA]
                          | ((unsigned)m9s[sB] << 9)
                          | ((unsigned)m9s[sC] << 18);
        const bool active = (mask != 0u);

        f32x4 acc = {0.f, 0.f, 0.f, 0.f};
        while (mask) {
            int l = __ffs(mask) - 1;        // tap index == weight k
            mask &= mask - 1;
            int fsel = l < 9 ? fhs[sA] : (l < 18 ? fhs[sB] : fhs[sC]);
            int w    = l < 9 ? l        : (l < 18 ? l - 9    : l - 18);
            int fg = __shfl(fsel, (gw << 4) + w, 64);
            h16x2 fh2 = as_h2(fg);
            const uint4* wl = reinterpret_cast<const uint4*>(
                                  &wlds[l * COUT_ + q * 4]);
            uint4 wv = *wl;                 // 4 channels' (w0,w1) half2 pairs
            acc.x = __builtin_amdgcn_fdot2(fh2, as_h2(wv.x), acc.x, false);
            acc.y = __builtin_amdgcn_fdot2(fh2, as_h2(wv.y), acc.y, false);
            acc.z = __builtin_amdgcn_fdot2(fh2, as_h2(wv.z), acc.z, false);
            acc.w = __builtin_amdgcn_fdot2(fh2, as_h2(wv.w), acc.w, false);
        }

        // ---- LayerNorm via DPP allreduce across the 16-lane group ----
        float s  = acc.x + acc.y + acc.z + acc.w;
        float s2 = acc.x * acc.x + acc.y * acc.y + acc.z * acc.z
                 + acc.w * acc.w;
        s  = row16_allreduce_add(s);
        s2 = row16_allreduce_add(s2);
        float mu  = s * (1.0f / COUT_);
        float var = s2 * (1.0f / COUT_) - mu * mu;
        float inv = rsqrtf(var + EPS_);

        f32x4 r = {0.f, 0.f, 0.f, 0.f};
        if (active) {
            f32x4 t = (acc - mu) * inv;     // vector-scalar ops (ext_vector)
            t = t * gm + bt;
            r.x = fmaxf(t.x, 0.f);
            r.y = fmaxf(t.y, 0.f);
            r.z = fmaxf(t.z, 0.f);
            r.w = fmaxf(t.w, 0.f);
        }

        if (cell_ok) {
            const int bz = bz0 + j;
            size_t obase = ((size_t)((bz * H_ + y) * W_ + x)) * COUT_ + q * 4;
            __builtin_nontemporal_store(
                r, reinterpret_cast<f32x4*>(&out[obase]));
        }
    }
}

extern "C" void kernel_launch(void* const* d_in, const int* in_sizes, int n_in,
                              void* d_out, int out_size, void* d_ws, size_t ws_size,
                              hipStream_t stream) {
    const float* feat    = (const float*)d_in[0];   // (N, 2)
    const float* weight  = (const float*)d_in[1];   // (27, 2, 64)
    const float* gamma   = (const float*)d_in[2];   // (64,)
    const float* beta    = (const float*)d_in[3];   // (64,)
    const int*   scatter = (const int*)d_in[4];     // (27, N)
    float* out = (float*)d_out;                     // (CELLS, 64)

    int* map = (int*)d_ws;                          // CELLS * 4 B = 3.84 MB

    (void)hipMemsetAsync(map, 0xFF, (size_t)CELLS_ * sizeof(int), stream);
    {
        int block = 256;
        int grid = (N_ + block - 1) / block;
        fill_map_kernel<<<grid, block, 0, stream>>>(scatter, map);
    }

    // fused gather-conv + LN + ReLU: 16 cells x ZCHUNK z-planes per block
    {
        dim3 block(256, 1, 1);
        dim3 grid((W_ + 15) / 16, H_, (B_ * D_) / ZCHUNK);  // 13 x 200 x 4
        gather_cell16_kernel<<<grid, block, 0, stream>>>(feat, weight, gamma,
                                                         beta, map, out);
    }
}

// Round 9
// 278.060 us; speedup vs baseline: 1.9189x; 1.0041x over previous
//
#include <hip/hip_runtime.h>
#include <cstddef>
#include <cstdint>

#define B_ 2
#define D_ 12
#define H_ 200
#define W_ 200
#define HW_ (H_ * W_)
#define CELLS_ (B_ * D_ * H_ * W_)   // 960000
#define N_ 60000
#define CIN_ 2
#define COUT_ 64
#define K27 27
#define EPS_ 1e-5f
#define ZCHUNK 6                      // z-planes per block (12 % 6 == 0)

// padded dense feature map: [B][D+2][H+2][W+2] of packed fp16x2 (4 B/cell)
#define PD (D_ + 2)
#define PH (H_ + 2)
#define PW (W_ + 2)
#define PLANE (PH * PW)               // 40804
#define PF_INTS (B_ * PD * PLANE)     // 1,142,512 ints = 4.57 MB

typedef float  f32x4 __attribute__((ext_vector_type(4)));
typedef __fp16 h16x8 __attribute__((ext_vector_type(8)));
typedef __fp16 h16x2 __attribute__((ext_vector_type(2)));

union h2u   { h16x2 h; int u; };
union fragu { h16x8 v; int i[4]; };

__device__ __forceinline__ int pack_h2(float a, float b) {
    h2u t; t.h = __builtin_amdgcn_cvt_pkrtz(a, b); return t.u;
}

// ---------------------------------------------------------------------------
// Kernel A: build dense zero-padded fp16 feature map from scatter[13] (the
// identity tap = each point's own cell; always in-bounds, no duplicates).
// Padding (1 cell each side in z,y,x) makes ALL 27 neighbor reads valid ->
// the main kernel has no bounds checks, no map probing, no ballot masks.
// ---------------------------------------------------------------------------
__global__ void build_featmap_kernel(const int* __restrict__ scatter,
                                     const float* __restrict__ feat,
                                     int* __restrict__ pf) {
    int n = blockIdx.x * blockDim.x + threadIdx.x;
    if (n >= N_) return;
    int lin = scatter[13 * N_ + n];
    int b = lin / (D_ * HW_);
    int r = lin % (D_ * HW_);
    int z = r / HW_;  r %= HW_;
    int y = r / W_;
    int x = r % W_;
    float2 f = *reinterpret_cast<const float2*>(feat + n * CIN_);
    pf[((b * PD + z + 1) * PH + y + 1) * PW + (x + 1)] = pack_h2(f.x, f.y);
}

// ---------------------------------------------------------------------------
// DPP 16-lane allreduce-add (VALU pipe, no LDS). Verified in rounds 3-8.
// ---------------------------------------------------------------------------
template <int CTRL>
__device__ __forceinline__ float dpp_add(float v) {
    int t = __builtin_amdgcn_update_dpp(
        0, __float_as_int(v), CTRL, 0xF, 0xF, true);
    return v + __int_as_float(t);
}
__device__ __forceinline__ float row16_allreduce_add(float v) {
    v = dpp_add<0x140>(v);  // row_mirror
    v = dpp_add<0x141>(v);  // row_half_mirror
    v = dpp_add<0x4E>(v);   // quad_perm i^2
    v = dpp_add<0xB1>(v);   // quad_perm i^1
    return v;
}

// ---------------------------------------------------------------------------
// Kernel B, round-9: DENSE MFMA CONV. One wave computes 16 cells x 64 ch per
// z-iter as D[16,64] = A[16,K=64] * B[K=64,54->64pad] via 8x
// v_mfma_f32_16x16x32_f16 (4 N-tiles x 2 K-steps, fp32 accumulate).
//  - A frag = 4 raw dwords from the packed featmap (tap t = 4*grp+16*s+i;
//    slot maps of A and B use the SAME enumeration, so the HW k-permutation
//    cancels; k>=54 slots zeroed in B and read featmap pad-zero in A).
//  - per-lane tap voffsets are z-invariant (z enters via a uniform base).
//  - active flag: OR of the 8 A dwords (mask sign bits) + one ballot;
//    OR-fold across the 4 lane groups gives per-cell activity.
//  - LN: per lane 4 cells x 4 values; row16 DPP allreduce per cell (the
//    cell's 64 channels live in exactly one 16-lane DPP row). D mapping
//    col=lane&15 (channel), row=(lane>>4)*4+reg (cell) [HW-verified].
//  - stores: per-lane-constant base + immediate offsets, nontemporal.
// No map, no LDS, no divergent inner loop, no per-hit shuffles.
// ---------------------------------------------------------------------------
__global__ __launch_bounds__(256) void conv_mfma_kernel(
        const int* __restrict__ pf,
        const float* __restrict__ weight,
        const float* __restrict__ gamma,
        const float* __restrict__ beta,
        float* __restrict__ out) {
    const int tid  = threadIdx.x;
    const int lane = tid & 63;
    const int wid  = tid >> 6;          // wave in block, 0..3
    const int col  = lane & 15;         // cell-in-strip (A row) / channel-low
    const int grp  = lane >> 4;         // k-slice group, 0..3

    const int ps = blockIdx.x * 4 + wid;        // plane strip id, 0..2499
    const int f  = ps * 16 + col;               // in-plane flat cell
    const int y  = f / W_;
    const int x  = f % W_;

    const int bz0 = blockIdx.y * ZCHUNK;        // first bz of chunk
    const int b   = (bz0 >= D_) ? 1 : 0;        // chunk never straddles b
    const int z0  = bz0 - b * D_;

    // ---- per-lane A voffsets: 2 K-steps x 4 taps (z-invariant) ----
    // tap t -> (dz,dy,dx) in 0..2 == true offset + 1 (matches padding bias)
    int voff[2][4];
    #pragma unroll
    for (int s = 0; s < 2; ++s) {
        #pragma unroll
        for (int i = 0; i < 4; ++i) {
            int t = grp * 4 + 16 * s + i;
            if (t <= 26) {
                int dz = t / 9, rr = t % 9, dy = rr / 3, dx = rr % 3;
                voff[s][i] = dz * PLANE + (y + dy) * PW + (x + dx);
            } else {
                voff[s][i] = 0;         // pad slot: reads padding zero
            }
        }
    }

    // ---- B fragments: W54[k][c], k = tap*2+p, built once per block ----
    // slot (grp,s,j2) carries tap t = grp*4+16*s+j2 (same map as A) with
    // p=0 in low half, p=1 in high half (matches featmap packing).
    fragu bfr[2][4];
    #pragma unroll
    for (int s = 0; s < 2; ++s) {
        #pragma unroll
        for (int nt = 0; nt < 4; ++nt) {
            #pragma unroll
            for (int j2 = 0; j2 < 4; ++j2) {
                int t = grp * 4 + 16 * s + j2;
                float w0 = 0.f, w1 = 0.f;
                if (t <= 26) {
                    w0 = weight[t * (CIN_ * COUT_) + nt * 16 + col];
                    w1 = weight[t * (CIN_ * COUT_) + COUT_ + nt * 16 + col];
                }
                bfr[s][nt].i[j2] = pack_h2(w0, w1);
            }
        }
    }

    // per-lane channel params for the 4 N-tiles
    float gmv[4], btv[4];
    #pragma unroll
    for (int nt = 0; nt < 4; ++nt) {
        gmv[nt] = gamma[nt * 16 + col];
        btv[nt] = beta[nt * 16 + col];
    }

    // per-lane store base: cell (ps*16 + grp*4 + jj), channel col + nt*16
    const int obl = (ps * 16 + grp * 4) * COUT_ + col;

    for (int j = 0; j < ZCHUNK; ++j) {
        const int z  = z0 + j;
        const int bz = bz0 + j;
        const int zb = (b * PD + z) * PLANE;    // uniform featmap base

        // ---- A loads: 8 packed-fp16x2 dwords = both K-step fragments ----
        fragu af0, af1;
        #pragma unroll
        for (int i = 0; i < 4; ++i) af0.i[i] = pf[zb + voff[0][i]];
        #pragma unroll
        for (int i = 0; i < 4; ++i) af1.i[i] = pf[zb + voff[1][i]];

        // ---- active: any nonzero tap value among this lane's slots ----
        int nz = 0;
        #pragma unroll
        for (int i = 0; i < 4; ++i) nz |= af0.i[i] & 0x7FFF7FFF;
        #pragma unroll
        for (int i = 0; i < 4; ++i) nz |= af1.i[i] & 0x7FFF7FFF;
        unsigned long long bal = __ballot(nz != 0);
        unsigned wfold = (unsigned)bal | (unsigned)(bal >> 16)
                       | (unsigned)(bal >> 32) | (unsigned)(bal >> 48);
        unsigned act4 = (wfold >> (grp * 4)) & 0xF;   // this lane's 4 cells

        // ---- 8 MFMAs: acc[nt] over 2 K-steps ----
        f32x4 acc[4];
        #pragma unroll
        for (int nt = 0; nt < 4; ++nt) {
            acc[nt] = (f32x4){0.f, 0.f, 0.f, 0.f};
            acc[nt] = __builtin_amdgcn_mfma_f32_16x16x32_f16(
                          af0.v, bfr[0][nt].v, acc[nt], 0, 0, 0);
            acc[nt] = __builtin_amdgcn_mfma_f32_16x16x32_f16(
                          af1.v, bfr[1][nt].v, acc[nt], 0, 0, 0);
        }

        // ---- LN + ReLU + store, 4 cells per lane ----
        float* op = out + (size_t)bz * (HW_ * COUT_) + obl;
        #pragma unroll
        for (int jj = 0; jj < 4; ++jj) {
            float a0 = acc[0][jj], a1 = acc[1][jj],
                  a2 = acc[2][jj], a3 = acc[3][jj];
            float s  = a0 + a1 + a2 + a3;
            float s2 = a0 * a0 + a1 * a1 + a2 * a2 + a3 * a3;
            s  = row16_allreduce_add(s);
            s2 = row16_allreduce_add(s2);
            float mu  = s * (1.0f / COUT_);
            float var = s2 * (1.0f / COUT_) - mu * mu;
            float inv = rsqrtf(var + EPS_);
            bool actj = (act4 >> jj) & 1;
            #pragma unroll
            for (int nt = 0; nt < 4; ++nt) {
                float v  = acc[nt][jj];
                float rv = fmaxf((v - mu) * inv * gmv[nt] + btv[nt], 0.0f);
                rv = actj ? rv : 0.0f;     // inactive -> exact zeros
                __builtin_nontemporal_store(rv, op + jj * COUT_ + nt * 16);
            }
        }
    }
}

extern "C" void kernel_launch(void* const* d_in, const int* in_sizes, int n_in,
                              void* d_out, int out_size, void* d_ws, size_t ws_size,
                              hipStream_t stream) {
    const float* feat    = (const float*)d_in[0];   // (N, 2)
    const float* weight  = (const float*)d_in[1];   // (27, 2, 64)
    const float* gamma   = (const float*)d_in[2];   // (64,)
    const float* beta    = (const float*)d_in[3];   // (64,)
    const int*   scatter = (const int*)d_in[4];     // (27, N)
    float* out = (float*)d_out;                     // (CELLS, 64)

    int* pf = (int*)d_ws;                           // 4.57 MB padded featmap

    (void)hipMemsetAsync(pf, 0, (size_t)PF_INTS * sizeof(int), stream);
    {
        int block = 256;
        int grid = (N_ + block - 1) / block;
        build_featmap_kernel<<<grid, block, 0, stream>>>(scatter, feat, pf);
    }

    // dense MFMA conv + LN + ReLU: 4 waves/block, 16 cells/wave, 6 z/block
    {
        dim3 block(256, 1, 1);
        dim3 grid((HW_ / 16) / 4, (B_ * D_) / ZCHUNK, 1);   // 625 x 4
        conv_mfma_kernel<<<grid, block, 0, stream>>>(pf, weight, gamma,
                                                     beta, out);
    }
}